// Round 2
// baseline (244.663 us; speedup 1.0000x reference)
//
#include <hip/hip_runtime.h>

// LongTermSpectralFlatness: x (32, 3000, 201, 2) fp32 -> flatness (32, 3000, 1) fp32
//
// Math (t >= 1):
//   s[t,f]     = (re^2+im^2) * scale[f] * hamm_sq_sum(25)/16000/10
//   welch[t,f] = mean(s[t-10..t-1, f])                  (cnt = max(min(t,10),1))
//   am[t,f]    = mean(welch[t-30..t-1, f]) + 1e-5
//   gm[t,f]    = exp(mean(log(welch[t-30..t-1,f]+1e-5)))   (the -eps+eps cancels!)
//   flat[t]    = log10(2) * sum_f ( log2(am) - mean(log2(welch+eps)) ),  flat[0] = 0
//
// R1: LTILE 190->60 (1600 blocks, ~6 blocks/CU vs 2) and batched butterflies
// (10 independent 6-step shfl_xor reductions per group -> ILP hides ds_swizzle
// latency). R0 was latency-bound: Occupancy 17.8%, VALUBusy 16%, HBM 9.6%.

constexpr int TT = 3000;
constexpr int FF = 201;
constexpr int BB = 32;
constexpr int W1 = 10;
constexpr int W2 = 30;
constexpr int HALO = 40;   // W1 + W2
constexpr int LTILE = 60;  // output frames per tile
constexpr int NT = 50;     // 50 * 60 = 3000
#define EPSV 1e-5f
#define CSCALE (9.935f / 160000.0f)  // hamming_sq_sum(25)/16000/M
#define LOG10_2 0.3010299956639812f

// One 30-frame super-group. DYN selects dynamic window counts (tile 0, t<30).
#define SUPERGROUP(DYN)                                                        \
  {                                                                            \
    /* refresh running sums from rings: kills sliding-subtract drift */        \
    float a0 = 0.f, a1 = 0.f, a2 = 0.f;                                        \
    _Pragma("unroll") for (int j = 0; j < W2; ++j) {                           \
      a0 += w_ring[j]; a1 += l_ring[j];                                        \
    }                                                                          \
    _Pragma("unroll") for (int j = 0; j < W1; ++j) a2 += s_ring[j];            \
    wsum = a0; lsum = a1; ssum = a2;                                           \
    _Pragma("unroll") for (int g = 0; g < 3; ++g) {                            \
      /* prefetch next 10 frames into nxt */                                   \
      _Pragma("unroll") for (int j = 0; j < 10; ++j) {                         \
        int tt = min(tstart + kbase + m0 + (g + 1) * 10 + j, tmax);            \
        nxt[j] = xb[(size_t)tt * FF + f];                                      \
      }                                                                        \
      float rr[10];                                                            \
      /* scan: cheap dependent ring updates, contribs into rr[] */             \
      _Pragma("unroll") for (int j = 0; j < 10; ++j) {                         \
        const int slot30 = g * 10 + j;                                         \
        int t = t0 + m0 + g * 10 + j;                                          \
        float inv10, inv30;                                                    \
        if (DYN) {                                                             \
          inv10 = 1.0f / (float)max(min(t, W1), 1);                            \
          inv30 = 1.0f / (float)max(min(t, W2), 1);                            \
        } else {                                                               \
          inv10 = 0.1f;                                                        \
          inv30 = (1.0f / 30.0f);                                              \
        }                                                                      \
        float welch = ssum * inv10;                                            \
        float lw = __log2f(welch + EPSV);                                      \
        float am = fmaf(wsum, inv30, EPSV);                                    \
        float la = __log2f(am);                                                \
        rr[j] = (la - lsum * inv30) * LOG10_2;                                 \
        wsum += welch - w_ring[slot30]; w_ring[slot30] = welch;                \
        lsum += lw - l_ring[slot30];    l_ring[slot30] = lw;                   \
        float sv = fmaf(cur[j].x, cur[j].x, cur[j].y * cur[j].y) * cs;         \
        ssum += sv - s_ring[j]; s_ring[j] = sv;                                \
      }                                                                        \
      /* 10 independent butterflies: ILP hides ds_swizzle latency */           \
      _Pragma("unroll") for (int off = 32; off >= 1; off >>= 1) {              \
        _Pragma("unroll") for (int j = 0; j < 10; ++j)                         \
            rr[j] += __shfl_xor(rr[j], off, 64);                               \
      }                                                                        \
      if (lane == 0) {                                                         \
        _Pragma("unroll") for (int j = 0; j < 10; ++j)                         \
            part[wv][m0 + g * 10 + j] = rr[j];                                 \
      }                                                                        \
      _Pragma("unroll") for (int j = 0; j < 10; ++j) cur[j] = nxt[j];          \
    }                                                                          \
    m0 += 30;                                                                  \
  }

__global__ __launch_bounds__(256, 4)
void ltsf_kernel(const float2* __restrict__ x, float* __restrict__ out) {
  const int tid = threadIdx.x;
  const int tile = blockIdx.x;
  const int b = blockIdx.y;
  const int t0 = tile * LTILE;
  const bool first = (tile == 0);
  const int tstart = first ? 0 : (t0 - HALO);
  const int lane = tid & 63;
  const int wv = tid >> 6;

  // freq bin; lanes >= 201 are zero-scale (they contribute exactly 0)
  const int f = (tid < FF) ? tid : (FF - 1);
  float cs = (tid < FF) ? ((tid == 0 || tid == FF - 1) ? 1.0f : 2.0f) : 0.0f;
  cs *= CSCALE;

  const float2* xb = x + (size_t)b * TT * FF;
  const int tmax = t0 + LTILE - 1;  // clamp loads inside tile (3000 = 50*60)

  __shared__ float part[4][LTILE];

  float s_ring[W1], w_ring[W2], l_ring[W2];
#pragma unroll
  for (int j = 0; j < W1; ++j) s_ring[j] = 0.f;
#pragma unroll
  for (int j = 0; j < W2; ++j) { w_ring[j] = 0.f; l_ring[j] = 0.f; }
  float ssum = 0.f, wsum = 0.f, lsum = 0.f;

  float2 cur[10], nxt[10];

  // initial preload: frames tstart .. tstart+9
#pragma unroll
  for (int j = 0; j < 10; ++j) {
    int tt = min(tstart + j, tmax);
    cur[j] = xb[(size_t)tt * FF + f];
  }

  const int kbase = first ? 0 : HALO;
  int m0 = 0;

  if (!first) {
    // ---- warm-up A: 10 frames, s-ring only (t = tstart .. tstart+9) ----
    {
#pragma unroll
      for (int j = 0; j < 10; ++j) {
        int tt = min(tstart + 10 + j, tmax);
        nxt[j] = xb[(size_t)tt * FF + f];
      }
#pragma unroll
      for (int j = 0; j < 10; ++j) {
        float sv = fmaf(cur[j].x, cur[j].x, cur[j].y * cur[j].y) * cs;
        ssum += sv;
        s_ring[j] = sv;
      }
#pragma unroll
      for (int j = 0; j < 10; ++j) cur[j] = nxt[j];
    }
    // ---- warm-up B: 30 frames, welch/log pushes (t = tstart+10 .. tstart+39) ----
#pragma unroll
    for (int g = 0; g < 3; ++g) {
#pragma unroll
      for (int j = 0; j < 10; ++j) {
        int tt = min(tstart + 20 + g * 10 + j, tmax);
        nxt[j] = xb[(size_t)tt * FF + f];
      }
#pragma unroll
      for (int j = 0; j < 10; ++j) {
        const int slot30 = g * 10 + j;
        float welch = ssum * 0.1f;  // full 10-window here always (t0 >= 60)
        float lw = __log2f(welch + EPSV);
        wsum += welch; w_ring[slot30] = welch;
        lsum += lw;    l_ring[slot30] = lw;
        float sv = fmaf(cur[j].x, cur[j].x, cur[j].y * cur[j].y) * cs;
        ssum += sv - s_ring[j];
        s_ring[j] = sv;
      }
#pragma unroll
      for (int j = 0; j < 10; ++j) cur[j] = nxt[j];
    }
  }

  // ---- main: 2 super-groups of 30 output frames (LTILE = 60) ----
  if (first) {
    SUPERGROUP(true);   // t in [0,30): dynamic window counts
    SUPERGROUP(false);
  } else {
    SUPERGROUP(false);
    SUPERGROUP(false);
  }

  // ---- epilogue: sum the 4 wave partials per frame, write out ----
  __syncthreads();
  if (tid < LTILE) {
    float v = part[0][tid] + part[1][tid] + part[2][tid] + part[3][tid];
    if (first && tid == 0) v = 0.f;  // reference forces frame 0 to exactly 0
    out[(size_t)b * TT + t0 + tid] = v;
  }
}

extern "C" void kernel_launch(void* const* d_in, const int* in_sizes, int n_in,
                              void* d_out, int out_size, void* d_ws, size_t ws_size,
                              hipStream_t stream) {
  const float2* x = (const float2*)d_in[0];
  float* out = (float*)d_out;
  dim3 grid(NT, BB);
  ltsf_kernel<<<grid, 256, 0, stream>>>(x, out);
}

// Round 3
// 223.949 us; speedup vs baseline: 1.0925x; 1.0925x over previous
//
#include <hip/hip_runtime.h>

// LongTermSpectralFlatness: x (32, 3000, 201, 2) fp32 -> flatness (32, 3000, 1) fp32
//
// Math (t >= 1):
//   s[t,f]     = (re^2+im^2) * scale[f] * hamm_sq_sum(25)/16000/10
//   welch[t,f] = mean(s[t-10..t-1, f])                  (cnt = max(min(t,10),1))
//   am[t,f]    = mean(welch[t-30..t-1, f]) + 1e-5
//   gm[t,f]    = exp(mean(log(welch[t-30..t-1,f]+1e-5)))   (the -eps+eps cancels!)
//   flat[t]    = log10(2) * sum_f ( log2(am) - mean(log2(welch+eps)) ),  flat[0] = 0
//
// R2: R1 spilled (WRITE_SIZE 54.7 MB of scratch; VGPR capped at 64 by
// launch_bounds(256,4) vs ~140 live). Shrink live set under the 128-VGPR
// 4-wave/EU budget: prefetch depth 10->5, butterfly batch 10->5. Rings stay
// in registers (fully static indices via unrolled groups of 5).

constexpr int TT = 3000;
constexpr int FF = 201;
constexpr int BB = 32;
constexpr int W1 = 10;
constexpr int W2 = 30;
constexpr int HALO = 40;   // W1 + W2
constexpr int LTILE = 60;  // output frames per tile
constexpr int NT = 50;     // 50 * 60 = 3000
#define EPSV 1e-5f
#define CSCALE (9.935f / 160000.0f)  // hamming_sq_sum(25)/16000/M
#define LOG10_2 0.3010299956639812f

// One 30-frame super-group = 6 unrolled groups of 5 frames.
// DYN selects dynamic window counts (tile 0, t < 30).
#define SUPERGROUP(DYN)                                                        \
  {                                                                            \
    /* refresh running sums from rings: kills sliding-subtract drift */        \
    float a0 = 0.f, a1 = 0.f, a2 = 0.f;                                        \
    _Pragma("unroll") for (int j = 0; j < W2; ++j) {                           \
      a0 += w_ring[j]; a1 += l_ring[j];                                        \
    }                                                                          \
    _Pragma("unroll") for (int j = 0; j < W1; ++j) a2 += s_ring[j];            \
    wsum = a0; lsum = a1; ssum = a2;                                           \
    _Pragma("unroll") for (int g = 0; g < 6; ++g) {                            \
      /* prefetch next 5 frames */                                             \
      _Pragma("unroll") for (int j = 0; j < 5; ++j) {                          \
        int tt = min(tstart + kbase + m0 + (g + 1) * 5 + j, tmax);             \
        nxt[j] = xb[(size_t)tt * FF + f];                                      \
      }                                                                        \
      float rr[5];                                                             \
      _Pragma("unroll") for (int j = 0; j < 5; ++j) {                          \
        const int fr = g * 5 + j;        /* frame within super-group */        \
        const int slot30 = fr;                                                 \
        const int slot10 = fr % 10;                                            \
        int t = t0 + m0 + fr;                                                  \
        float inv10, inv30;                                                    \
        if (DYN) {                                                             \
          inv10 = 1.0f / (float)max(min(t, W1), 1);                            \
          inv30 = 1.0f / (float)max(min(t, W2), 1);                            \
        } else {                                                               \
          inv10 = 0.1f;                                                        \
          inv30 = (1.0f / 30.0f);                                              \
        }                                                                      \
        float welch = ssum * inv10;                                            \
        float lw = __log2f(welch + EPSV);                                      \
        float am = fmaf(wsum, inv30, EPSV);                                    \
        float la = __log2f(am);                                                \
        rr[j] = (la - lsum * inv30) * LOG10_2;                                 \
        wsum += welch - w_ring[slot30]; w_ring[slot30] = welch;                \
        lsum += lw - l_ring[slot30];    l_ring[slot30] = lw;                   \
        float sv = fmaf(cur[j].x, cur[j].x, cur[j].y * cur[j].y) * cs;         \
        ssum += sv - s_ring[slot10]; s_ring[slot10] = sv;                      \
      }                                                                        \
      /* 5 independent butterflies: ILP hides ds_swizzle latency */            \
      _Pragma("unroll") for (int off = 32; off >= 1; off >>= 1) {              \
        _Pragma("unroll") for (int j = 0; j < 5; ++j)                          \
            rr[j] += __shfl_xor(rr[j], off, 64);                               \
      }                                                                        \
      if (lane == 0) {                                                         \
        _Pragma("unroll") for (int j = 0; j < 5; ++j)                          \
            part[wv][m0 + g * 5 + j] = rr[j];                                  \
      }                                                                        \
      _Pragma("unroll") for (int j = 0; j < 5; ++j) cur[j] = nxt[j];           \
    }                                                                          \
    m0 += 30;                                                                  \
  }

__global__ __launch_bounds__(256, 4)
void ltsf_kernel(const float2* __restrict__ x, float* __restrict__ out) {
  const int tid = threadIdx.x;
  const int tile = blockIdx.x;
  const int b = blockIdx.y;
  const int t0 = tile * LTILE;
  const bool first = (tile == 0);
  const int tstart = first ? 0 : (t0 - HALO);
  const int lane = tid & 63;
  const int wv = tid >> 6;

  // freq bin; lanes >= 201 are zero-scale (they contribute exactly 0)
  const int f = (tid < FF) ? tid : (FF - 1);
  float cs = (tid < FF) ? ((tid == 0 || tid == FF - 1) ? 1.0f : 2.0f) : 0.0f;
  cs *= CSCALE;

  const float2* xb = x + (size_t)b * TT * FF;
  const int tmax = t0 + LTILE - 1;  // clamp loads inside tile (3000 = 50*60)

  __shared__ float part[4][LTILE];

  float s_ring[W1], w_ring[W2], l_ring[W2];
#pragma unroll
  for (int j = 0; j < W1; ++j) s_ring[j] = 0.f;
#pragma unroll
  for (int j = 0; j < W2; ++j) { w_ring[j] = 0.f; l_ring[j] = 0.f; }
  float ssum = 0.f, wsum = 0.f, lsum = 0.f;

  float2 cur[5], nxt[5];

  // initial preload: frames tstart .. tstart+4
#pragma unroll
  for (int j = 0; j < 5; ++j) {
    int tt = min(tstart + j, tmax);
    cur[j] = xb[(size_t)tt * FF + f];
  }

  const int kbase = first ? 0 : HALO;
  int m0 = 0;

  if (!first) {
    // ---- warm-up A: 10 frames, s-ring only (stream k = 0..9) ----
#pragma unroll
    for (int g = 0; g < 2; ++g) {
#pragma unroll
      for (int j = 0; j < 5; ++j) {
        int tt = min(tstart + (g + 1) * 5 + j, tmax);
        nxt[j] = xb[(size_t)tt * FF + f];
      }
#pragma unroll
      for (int j = 0; j < 5; ++j) {
        float sv = fmaf(cur[j].x, cur[j].x, cur[j].y * cur[j].y) * cs;
        ssum += sv;
        s_ring[g * 5 + j] = sv;
      }
#pragma unroll
      for (int j = 0; j < 5; ++j) cur[j] = nxt[j];
    }
    // ---- warm-up B: 30 frames, welch/log pushes (stream k = 10..39) ----
#pragma unroll
    for (int g = 0; g < 6; ++g) {
#pragma unroll
      for (int j = 0; j < 5; ++j) {
        int tt = min(tstart + 15 + g * 5 + j, tmax);
        nxt[j] = xb[(size_t)tt * FF + f];
      }
#pragma unroll
      for (int j = 0; j < 5; ++j) {
        const int fr = g * 5 + j;
        float welch = ssum * 0.1f;  // full 10-window here always (t0 >= 60)
        float lw = __log2f(welch + EPSV);
        wsum += welch; w_ring[fr] = welch;
        lsum += lw;    l_ring[fr] = lw;
        float sv = fmaf(cur[j].x, cur[j].x, cur[j].y * cur[j].y) * cs;
        ssum += sv - s_ring[fr % 10];
        s_ring[fr % 10] = sv;
      }
#pragma unroll
      for (int j = 0; j < 5; ++j) cur[j] = nxt[j];
    }
  }

  // ---- main: 2 super-groups of 30 output frames (LTILE = 60) ----
  if (first) {
    SUPERGROUP(true);   // t in [0,30): dynamic window counts
    SUPERGROUP(false);
  } else {
    SUPERGROUP(false);
    SUPERGROUP(false);
  }

  // ---- epilogue: sum the 4 wave partials per frame, write out ----
  __syncthreads();
  if (tid < LTILE) {
    float v = part[0][tid] + part[1][tid] + part[2][tid] + part[3][tid];
    if (first && tid == 0) v = 0.f;  // reference forces frame 0 to exactly 0
    out[(size_t)b * TT + t0 + tid] = v;
  }
}

extern "C" void kernel_launch(void* const* d_in, const int* in_sizes, int n_in,
                              void* d_out, int out_size, void* d_ws, size_t ws_size,
                              hipStream_t stream) {
  const float2* x = (const float2*)d_in[0];
  float* out = (float*)d_out;
  dim3 grid(NT, BB);
  ltsf_kernel<<<grid, 256, 0, stream>>>(x, out);
}